// Round 1
// baseline (1008.061 us; speedup 1.0000x reference)
//
#include <hip/hip_runtime.h>

// ---------------------------------------------------------------------------
// NonLocalBlockND, fp32 correctness-first baseline.
//
// Shapes: B=4, C=256, H=W=48 (N=2304), CI=128, cat=768, COUT=1024.
//
// Pipeline:
//   k_proj   : all 9 conv1x1 projections (g/theta/phi for x,x1,x2) -> proj
//   per batch b:
//     k_score  : F_i = Theta_i^T @ Phi_i  (3 x 2304 x 2304 raw scores)
//     k_softsum: row softmax of F0,F1,F2; A = sum -> written into F0 slot
//     k_pv     : partials of y[jc][q] = sum_m G[jc][m] * A[q][m]  (K-split x6)
//     k_pvred  : y[b] = sum of 6 partials
//   k_zcat   : z_j = W_j @ y_j + b + x_j residual, concat, *dw_w + dw_b -> dwcat
//   k_final  : out = x_in + p * (pw_w @ dwcat + pw_b)
//
// ws layout (floats):
//   [0, PROJ_SZ)            proj  (9,B,CI,N)   -- later aliased by dwcat (B,768,N)
//   [PROJ_SZ, +3*N*N)       F: 3 score slots (per current batch);
//                           slot0 becomes summed A; slots1-2 reused as pv partials
//   [PROJ_SZ+3NN, +B*384*N) y     (B, 384, N)
//   total = 30,081,024 floats = 120.3 MB
// ---------------------------------------------------------------------------

constexpr int B_  = 4;
constexpr int C_  = 256;
constexpr int N_  = 2304;
constexpr int CI_ = 128;
constexpr long long NN_ = (long long)N_ * N_;          // 5,308,416

constexpr size_t PROJ_SZ = (size_t)9 * B_ * CI_ * N_;  // 10,616,832
constexpr size_t F_SZ    = (size_t)3 * N_ * N_;        // 15,925,248

struct ProjArgs { const float* src[3]; const float* w[9]; const float* bias[9]; };
struct ZArgs    { const float* Wm[3]; const float* Wmb[3]; const float* x[3];
                  const float* dww; const float* dwb; };

// Load a 64x64 A-tile (row-major, row stride gstride) into As[64][65].
// float4 global loads, scalar LDS stores (65-stride kills row-bank aliasing).
__device__ __forceinline__ void load_A64(float* As, const float* g, size_t gstride, int t) {
  #pragma unroll
  for (int i = 0; i < 4; ++i) {
    int idx = t + i * 256;
    int r = idx >> 4, k4 = (idx & 15) << 2;
    float4 v = *(const float4*)(g + (size_t)r * gstride + k4);
    As[r * 65 + k4 + 0] = v.x;
    As[r * 65 + k4 + 1] = v.y;
    As[r * 65 + k4 + 2] = v.z;
    As[r * 65 + k4 + 3] = v.w;
  }
}

// Load a 64x128 B-tile (k-major, row stride gstride) into Bs[64][128], float4.
__device__ __forceinline__ void load_B64x128(float* Bs, const float* g, size_t gstride, int t) {
  #pragma unroll
  for (int i = 0; i < 8; ++i) {
    int idx = t + i * 256;
    int k = idx >> 5, q4 = (idx & 31) << 2;
    *(float4*)(Bs + k * 128 + q4) = *(const float4*)(g + (size_t)k * gstride + q4);
  }
}

// One 64-deep K-chunk of the 64x128 tile GEMM; 4x8 register tile per thread.
template<int BSTR>
__device__ __forceinline__ void mm_chunk(const float* As, const float* Bs,
                                         float (&acc)[4][8], int tx, int ty) {
  #pragma unroll 8
  for (int k = 0; k < 64; ++k) {
    float a0 = As[(ty * 4 + 0) * 65 + k];
    float a1 = As[(ty * 4 + 1) * 65 + k];
    float a2 = As[(ty * 4 + 2) * 65 + k];
    float a3 = As[(ty * 4 + 3) * 65 + k];
    float4 b0 = *(const float4*)(Bs + k * BSTR + tx * 8);
    float4 b1 = *(const float4*)(Bs + k * BSTR + tx * 8 + 4);
    float bb[8] = {b0.x, b0.y, b0.z, b0.w, b1.x, b1.y, b1.z, b1.w};
    #pragma unroll
    for (int cc = 0; cc < 8; ++cc) {
      acc[0][cc] = fmaf(a0, bb[cc], acc[0][cc]);
      acc[1][cc] = fmaf(a1, bb[cc], acc[1][cc]);
      acc[2][cc] = fmaf(a2, bb[cc], acc[2][cc]);
      acc[3][cc] = fmaf(a3, bb[cc], acc[3][cc]);
    }
  }
}

// ---------------- k_proj: out[p][b][m][q] = sum_c w_p[m][c]*src[c][q] + bias --
__global__ __launch_bounds__(256) void k_proj(ProjArgs a, float* proj) {
  __shared__ float As[64 * 65];
  __shared__ float Bs[64 * 128];
  const int t = threadIdx.x, tx = t & 15, ty = t >> 4;
  const int q0 = blockIdx.x * 128;
  const int m0 = blockIdx.y * 64;
  const int p  = blockIdx.z % 9;
  const int b  = blockIdx.z / 9;
  const float* w   = a.w[p];
  const float* src = a.src[p / 3] + (size_t)b * C_ * N_;
  float* dst = proj + ((size_t)p * B_ + b) * CI_ * N_;
  float acc[4][8] = {};
  for (int kb = 0; kb < C_; kb += 64) {
    load_A64(As, w + (size_t)m0 * C_ + kb, C_, t);
    load_B64x128(Bs, src + (size_t)kb * N_ + q0, N_, t);
    __syncthreads();
    mm_chunk<128>(As, Bs, acc, tx, ty);
    __syncthreads();
  }
  const float* bias = a.bias[p];
  #pragma unroll
  for (int ri = 0; ri < 4; ++ri) {
    int m = m0 + ty * 4 + ri;
    float bv = bias[m];
    float* dr = dst + (size_t)m * N_ + q0 + tx * 8;
    *(float4*)(dr + 0) = make_float4(acc[ri][0] + bv, acc[ri][1] + bv,
                                     acc[ri][2] + bv, acc[ri][3] + bv);
    *(float4*)(dr + 4) = make_float4(acc[ri][4] + bv, acc[ri][5] + bv,
                                     acc[ri][6] + bv, acc[ri][7] + bv);
  }
}

// ---------------- k_score: F[i][q][k] = sum_ci TH[ci][q] * PH[ci][k] ---------
__global__ __launch_bounds__(256) void k_score(const float* proj, float* F, int b) {
  __shared__ float As[64 * 65];   // theta^T tile: As[q][ci]
  __shared__ float Bs[64 * 128];  // phi tile:     Bs[ci][k]
  const int t = threadIdx.x, tx = t & 15, ty = t >> 4;
  const int k0 = blockIdx.x * 128;
  const int q0 = blockIdx.y * 64;
  const int br = blockIdx.z;
  const float* TH = proj + ((size_t)(br * 3 + 1) * B_ + b) * CI_ * N_;
  const float* PH = proj + ((size_t)(br * 3 + 2) * B_ + b) * CI_ * N_;
  float acc[4][8] = {};
  for (int cb = 0; cb < CI_; cb += 64) {
    #pragma unroll
    for (int i2 = 0; i2 < 16; ++i2) {        // transpose-store theta
      int idx = t + i2 * 256;
      int ci = idx >> 6, q = idx & 63;
      As[q * 65 + ci] = TH[(size_t)(cb + ci) * N_ + q0 + q];
    }
    load_B64x128(Bs, PH + (size_t)cb * N_ + k0, N_, t);
    __syncthreads();
    mm_chunk<128>(As, Bs, acc, tx, ty);
    __syncthreads();
  }
  float* dst = F + (size_t)br * NN_ + (size_t)q0 * N_ + k0;
  #pragma unroll
  for (int ri = 0; ri < 4; ++ri) {
    float* dr = dst + (size_t)(ty * 4 + ri) * N_ + tx * 8;
    *(float4*)(dr + 0) = make_float4(acc[ri][0], acc[ri][1], acc[ri][2], acc[ri][3]);
    *(float4*)(dr + 4) = make_float4(acc[ri][4], acc[ri][5], acc[ri][6], acc[ri][7]);
  }
}

// ---------------- k_softsum: A-row = sum_i softmax(F_i row) -> F0 ------------
__device__ __forceinline__ float blk_red(float v, bool is_max, float* red) {
  #pragma unroll
  for (int o = 32; o; o >>= 1) {
    float u = __shfl_xor(v, o);
    v = is_max ? fmaxf(v, u) : v + u;
  }
  int w = threadIdx.x >> 6;
  __syncthreads();
  if ((threadIdx.x & 63) == 0) red[w] = v;
  __syncthreads();
  float r = red[0];
  #pragma unroll
  for (int j = 1; j < 4; ++j) r = is_max ? fmaxf(r, red[j]) : r + red[j];
  return r;
}

__global__ __launch_bounds__(256) void k_softsum(float* F) {
  __shared__ float red[4];
  const int q = blockIdx.x, t = threadIdx.x;
  float raw[3][9];
  #pragma unroll
  for (int i = 0; i < 3; ++i)
    #pragma unroll
    for (int s = 0; s < 9; ++s)
      raw[i][s] = F[(size_t)i * NN_ + (size_t)q * N_ + t + s * 256];
  float outv[9] = {};
  #pragma unroll
  for (int i = 0; i < 3; ++i) {
    float m = -3.4e38f;
    #pragma unroll
    for (int s = 0; s < 9; ++s) m = fmaxf(m, raw[i][s]);
    m = blk_red(m, true, red);
    float ssum = 0.f;
    #pragma unroll
    for (int s = 0; s < 9; ++s) { raw[i][s] = expf(raw[i][s] - m); ssum += raw[i][s]; }
    ssum = blk_red(ssum, false, red);
    float inv = 1.f / ssum;
    #pragma unroll
    for (int s = 0; s < 9; ++s) outv[s] += raw[i][s] * inv;
  }
  #pragma unroll
  for (int s = 0; s < 9; ++s)
    F[(size_t)q * N_ + t + s * 256] = outv[s];
}

// ---------------- k_pv: part[s][jc][q] = sum_{m in split s} G[jc][m]*A[q][m] -
__global__ __launch_bounds__(256) void k_pv(const float* proj, const float* Ag,
                                            float* part, int b) {
  __shared__ float As[64 * 65];    // G rows (jc-local), cols m
  __shared__ float Bs[64 * 132];   // A^T tile: Bs[m][q], padded stride 132
  const int t = threadIdx.x, tx = t & 15, ty = t >> 4;
  const int q0  = blockIdx.x * 128;
  const int jc0 = blockIdx.y * 64;
  const int s   = blockIdx.z;
  const int j = jc0 >> 7, ci0 = jc0 & 127;
  const float* G = proj + ((size_t)(j * 3) * B_ + b) * CI_ * N_ + (size_t)ci0 * N_;
  float acc[4][8] = {};
  for (int mb = s * 384; mb < s * 384 + 384; mb += 64) {
    load_A64(As, G + mb, N_, t);
    #pragma unroll
    for (int i2 = 0; i2 < 8; ++i2) {         // transpose-store A tile
      int idx = t + i2 * 256;
      int q = idx >> 4, m4 = (idx & 15) << 2;
      float4 v = *(const float4*)(Ag + (size_t)(q0 + q) * N_ + mb + m4);
      Bs[(m4 + 0) * 132 + q] = v.x;
      Bs[(m4 + 1) * 132 + q] = v.y;
      Bs[(m4 + 2) * 132 + q] = v.z;
      Bs[(m4 + 3) * 132 + q] = v.w;
    }
    __syncthreads();
    mm_chunk<132>(As, Bs, acc, tx, ty);
    __syncthreads();
  }
  float* dst = part + ((size_t)s * 384 + jc0) * N_ + q0;
  #pragma unroll
  for (int ri = 0; ri < 4; ++ri) {
    float* dr = dst + (size_t)(ty * 4 + ri) * N_ + tx * 8;
    *(float4*)(dr + 0) = make_float4(acc[ri][0], acc[ri][1], acc[ri][2], acc[ri][3]);
    *(float4*)(dr + 4) = make_float4(acc[ri][4], acc[ri][5], acc[ri][6], acc[ri][7]);
  }
}

__global__ __launch_bounds__(256) void k_pvred(const float* part, float* yb) {
  int i4 = blockIdx.x * 256 + threadIdx.x;       // 221,184 float4 = 384*2304
  const float4* p4 = (const float4*)part;
  float4 a = p4[i4];
  #pragma unroll
  for (int s = 1; s < 6; ++s) {
    float4 v = p4[(size_t)s * 221184 + i4];
    a.x += v.x; a.y += v.y; a.z += v.z; a.w += v.w;
  }
  ((float4*)yb)[i4] = a;
}

// ---------------- k_zcat: dwcat = (W_j@y_j + Wb + x_j)*dw_w + dw_b -----------
__global__ __launch_bounds__(256) void k_zcat(const float* y, ZArgs za, float* dwcat) {
  __shared__ float As[64 * 65];
  __shared__ float Bs[64 * 128];
  const int t = threadIdx.x, tx = t & 15, ty = t >> 4;
  const int q0 = blockIdx.x * 128;
  const int c0 = blockIdx.y * 64;
  const int b  = blockIdx.z;
  const int j = c0 >> 8, cj = c0 & 255;
  const float* Wj = za.Wm[j];
  float acc[4][8] = {};
  for (int cb = 0; cb < CI_; cb += 64) {
    load_A64(As, Wj + (size_t)cj * CI_ + cb, CI_, t);
    load_B64x128(Bs, y + ((size_t)b * 384 + j * CI_ + cb) * N_ + q0, N_, t);
    __syncthreads();
    mm_chunk<128>(As, Bs, acc, tx, ty);
    __syncthreads();
  }
  #pragma unroll
  for (int ri = 0; ri < 4; ++ri) {
    int r  = ty * 4 + ri;
    int c  = c0 + r;          // 0..767 in cat
    int cl = cj + r;          // 0..255 within branch j
    float wb = za.Wmb[j][cl];
    float sc = za.dww[c], sb = za.dwb[c];
    const float* xr = za.x[j] + ((size_t)b * C_ + cl) * N_ + q0 + tx * 8;
    float* dr = dwcat + ((size_t)b * 768 + c) * N_ + q0 + tx * 8;
    float4 x0 = *(const float4*)(xr + 0);
    float4 x1 = *(const float4*)(xr + 4);
    *(float4*)(dr + 0) = make_float4((acc[ri][0] + wb + x0.x) * sc + sb,
                                     (acc[ri][1] + wb + x0.y) * sc + sb,
                                     (acc[ri][2] + wb + x0.z) * sc + sb,
                                     (acc[ri][3] + wb + x0.w) * sc + sb);
    *(float4*)(dr + 4) = make_float4((acc[ri][4] + wb + x1.x) * sc + sb,
                                     (acc[ri][5] + wb + x1.y) * sc + sb,
                                     (acc[ri][6] + wb + x1.z) * sc + sb,
                                     (acc[ri][7] + wb + x1.w) * sc + sb);
  }
}

// ---------------- k_final: out = x_in + p*(pw_w @ dwcat + pw_b) --------------
__global__ __launch_bounds__(256) void k_final(const float* dwcat, const float* pww,
                                               const float* pwb, const float* xin,
                                               const float* pp, float* out) {
  __shared__ float As[64 * 65];
  __shared__ float Bs[64 * 128];
  const int t = threadIdx.x, tx = t & 15, ty = t >> 4;
  const int q0 = blockIdx.x * 128;
  const int o0 = blockIdx.y * 64;
  const int b  = blockIdx.z;
  float acc[4][8] = {};
  for (int kb = 0; kb < 768; kb += 64) {
    load_A64(As, pww + (size_t)o0 * 768 + kb, 768, t);
    load_B64x128(Bs, dwcat + ((size_t)b * 768 + kb) * N_ + q0, N_, t);
    __syncthreads();
    mm_chunk<128>(As, Bs, acc, tx, ty);
    __syncthreads();
  }
  const float p = pp[0];
  #pragma unroll
  for (int ri = 0; ri < 4; ++ri) {
    int o = o0 + ty * 4 + ri;
    float bb = pwb[o];
    size_t base = ((size_t)b * 1024 + o) * N_ + q0 + tx * 8;
    float4 x0 = *(const float4*)(xin + base);
    float4 x1 = *(const float4*)(xin + base + 4);
    *(float4*)(out + base)     = make_float4(x0.x + p * (acc[ri][0] + bb),
                                             x0.y + p * (acc[ri][1] + bb),
                                             x0.z + p * (acc[ri][2] + bb),
                                             x0.w + p * (acc[ri][3] + bb));
    *(float4*)(out + base + 4) = make_float4(x1.x + p * (acc[ri][4] + bb),
                                             x1.y + p * (acc[ri][5] + bb),
                                             x1.z + p * (acc[ri][6] + bb),
                                             x1.w + p * (acc[ri][7] + bb));
  }
}

// ---------------------------------------------------------------------------
extern "C" void kernel_launch(void* const* d_in, const int* in_sizes, int n_in,
                              void* d_out, int out_size, void* d_ws, size_t ws_size,
                              hipStream_t stream) {
  const float* x0  = (const float*)d_in[0];
  const float* x1  = (const float*)d_in[1];
  const float* x2  = (const float*)d_in[2];
  const float* xin = (const float*)d_in[3];
  const float* g_w = (const float*)d_in[4];
  const float* g_b = (const float*)d_in[5];
  const float* thw[3] = {(const float*)d_in[6],  (const float*)d_in[10], (const float*)d_in[14]};
  const float* thb[3] = {(const float*)d_in[7],  (const float*)d_in[11], (const float*)d_in[15]};
  const float* phw[3] = {(const float*)d_in[8],  (const float*)d_in[12], (const float*)d_in[16]};
  const float* phb[3] = {(const float*)d_in[9],  (const float*)d_in[13], (const float*)d_in[17]};
  const float* Wm[3]  = {(const float*)d_in[18], (const float*)d_in[20], (const float*)d_in[22]};
  const float* Wmb[3] = {(const float*)d_in[19], (const float*)d_in[21], (const float*)d_in[23]};
  const float* dww = (const float*)d_in[24];
  const float* dwb = (const float*)d_in[25];
  const float* pww = (const float*)d_in[26];
  const float* pwb = (const float*)d_in[27];
  const float* pp  = (const float*)d_in[28];

  float* ws    = (float*)d_ws;
  float* proj  = ws;
  float* F     = ws + PROJ_SZ;
  float* part  = F + NN_;            // aliases F slots 1..2 (dead after softsum)
  float* y     = ws + PROJ_SZ + F_SZ;
  float* dwcat = ws;                 // aliases proj (dead after last k_pv)

  ProjArgs pa;
  pa.src[0] = x0; pa.src[1] = x1; pa.src[2] = x2;
  for (int v = 0; v < 3; ++v) {
    pa.w[v * 3 + 0] = g_w;      pa.bias[v * 3 + 0] = g_b;
    pa.w[v * 3 + 1] = thw[v];   pa.bias[v * 3 + 1] = thb[v];
    pa.w[v * 3 + 2] = phw[v];   pa.bias[v * 3 + 2] = phb[v];
  }
  ZArgs za;
  for (int j = 0; j < 3; ++j) { za.Wm[j] = Wm[j]; za.Wmb[j] = Wmb[j]; }
  za.x[0] = x0; za.x[1] = x1; za.x[2] = x2;
  za.dww = dww; za.dwb = dwb;

  k_proj<<<dim3(18, 2, 36), 256, 0, stream>>>(pa, proj);
  for (int b = 0; b < B_; ++b) {
    k_score  <<<dim3(18, 36, 3), 256, 0, stream>>>(proj, F, b);
    k_softsum<<<dim3(N_, 1, 1),  256, 0, stream>>>(F);
    k_pv     <<<dim3(18, 6, 6),  256, 0, stream>>>(proj, F, part, b);
    k_pvred  <<<dim3(864),       256, 0, stream>>>(part, y + (size_t)b * 384 * N_);
  }
  k_zcat <<<dim3(18, 12, 4), 256, 0, stream>>>(y, za, dwcat);
  k_final<<<dim3(18, 16, 4), 256, 0, stream>>>(dwcat, pww, pwb, xin, pp, (float*)d_out);
}

// Round 2
// 351.777 us; speedup vs baseline: 2.8656x; 2.8656x over previous
//
#include <hip/hip_runtime.h>

// ---------------------------------------------------------------------------
// NonLocalBlockND — bf16 MFMA pipeline (m97-style 128x128 tile GEMM core).
//
// All GEMM operands K-contiguous (A: MxK, B: N^T x K row-major), so every
// stage writes the layout its consumer wants:
//   k_cvtw  : weights fp32->bf16 (9 proj w, 3 Wz, pw)
//   k_cvtx  : x,x1,x2 (b,c,n) -> xbT (v,b,q,c) bf16   [transpose+convert]
//   k_proj  : proj = w @ xbT^T; theta/phi stored (q,ci) q-major, g stored (ci,m)
//   per (b, half):
//     k_score   : F[br][qloc][k] fp32 = thT x phT   (K=128)
//     k_softsum : A-row = sum of 3 softmaxes -> A_bf (b,q,m) bf16
//   k_pv    : Y[b][q][jc] = A_bf x gP               (K=2304, one launch)
//   k_zcat  : dwcatT[b][q][cg] = ((Wz@Y^T)+b+x)*dw_w+dw_b
//   k_final : out = x_in + p*(pw @ dwcatT^T + pw_b)
//
// ws (bytes, total 112,066,560 <= 120.3MB proven in round 1):
//   B_WB 0         bf16 proj weights (9x128x256, g duplicated)
//   B_WZ 589824    bf16 Wz (3x256x128)
//   B_PW 786432    bf16 pw (1024x768)
//   B_R1 2359296   xbT (3,4,2304,256) | later Y (4,2304,384)
//   B_R2 16515072  thT+phT (2x 3,4,2304,128) | later dwcatT (4,2304,768)
//   B_GP 30670848  gP (3,4,128,2304)
//   B_F  37748736  F (3,1152,2304) fp32, per (b,half)
//   B_A  69599232  A_bf (4,2304,2304) bf16
// ---------------------------------------------------------------------------

typedef __attribute__((ext_vector_type(8))) short bf16x8;
typedef __attribute__((ext_vector_type(4))) float f32x4;
typedef unsigned short u16;
struct alignas(8) u16x4 { u16 x, y, z, w; };

constexpr int B_ = 4, C_ = 256, N_ = 2304, CI_ = 128, NH_ = 1152;

constexpr size_t B_WB = 0;
constexpr size_t B_WZ = 589824;
constexpr size_t B_PW = 786432;
constexpr size_t B_R1 = 2359296;
constexpr size_t B_R2 = 16515072;
constexpr size_t B_GP = 30670848;
constexpr size_t B_F  = 37748736;
constexpr size_t B_A  = 69599232;

__device__ __forceinline__ u16 f2bf(float f) {
  unsigned u = __float_as_uint(f);
  u += 0x7fff + ((u >> 16) & 1);          // round-to-nearest-even
  return (u16)(u >> 16);
}

__device__ __forceinline__ void gload16(const void* g, void* l) {
  __builtin_amdgcn_global_load_lds((const __attribute__((address_space(1))) void*)g,
                                   (__attribute__((address_space(3))) void*)l,
                                   16, 0, 0);
}

// 128x128 output tile, BK=64, 256 threads (4 waves, 2x2 of 64x64), bf16 MFMA.
// Ab: A row-major (128 rows x K), ldaB bytes. Bb: B^T row-major (128 rows x K).
__device__ __forceinline__ void gemm_core(const char* Ab, int ldaB,
                                          const char* Bb, int ldbB,
                                          int kIters, f32x4 (&acc)[4][4],
                                          char* As, char* Bs) {
  const int t = (int)threadIdx.x, l = t & 63, w = t >> 6;
  const int arow = (w >> 1) * 64 + (l & 15);
  const int brow = (w & 1) * 64 + (l & 15);
  const int kb = ((l >> 4) * 8) * 2;        // byte offset of lane's k-slice
  for (int kt = 0; kt < kIters; ++kt) {
    const char* Ag = Ab + kt * 128;         // 64 bf16 = 128 B along K
    const char* Bg = Bb + kt * 128;
    #pragma unroll
    for (int c = 0; c < 4; ++c) {           // stage 16KB each, wave moves 1KB/call
      const int idx = c * 4096 + w * 1024 + l * 16;
      const int row = idx >> 7, colb = idx & 127;
      gload16(Ag + (size_t)row * ldaB + colb, As + c * 4096 + w * 1024);
      gload16(Bg + (size_t)row * ldbB + colb, Bs + c * 4096 + w * 1024);
    }
    __syncthreads();                        // compiler emits vmcnt(0) drain
    #pragma unroll
    for (int kk = 0; kk < 2; ++kk) {
      bf16x8 af[4], bfr[4];
      #pragma unroll
      for (int i = 0; i < 4; ++i) {
        af[i]  = *(const bf16x8*)(As + (arow + i * 16) * 128 + kk * 64 + kb);
        bfr[i] = *(const bf16x8*)(Bs + (brow + i * 16) * 128 + kk * 64 + kb);
      }
      #pragma unroll
      for (int mf = 0; mf < 4; ++mf)
        #pragma unroll
        for (int nf = 0; nf < 4; ++nf)
          acc[mf][nf] = __builtin_amdgcn_mfma_f32_16x16x32_bf16(
              af[mf], bfr[nf], acc[mf][nf], 0, 0, 0);
    }
    __syncthreads();
  }
}

// C/D fragment -> (row, col): row = rb + mf*16 + r, col = cb + nf*16  [m89]
#define EPI_SETUP \
  const int el = (int)threadIdx.x & 63, ew = (int)threadIdx.x >> 6; \
  const int rb = (ew >> 1) * 64 + ((el >> 4) << 2); \
  const int cb = (ew & 1) * 64 + (el & 15);

// ---------------- weight convert ----------------
struct CvtW { const float* s[13]; };
__global__ __launch_bounds__(256) void k_cvtw(CvtW cw, u16* dst) {
  const int seg = blockIdx.y;
  const int i = (blockIdx.x * 256 + threadIdx.x) * 4;
  const int sz = (seg == 12) ? 786432 : 32768;
  if (i >= sz) return;
  size_t off = (seg < 9) ? (size_t)seg * 32768
             : (seg < 12) ? 294912 + (size_t)(seg - 9) * 32768
                          : 393216;
  f32x4 v = *(const f32x4*)(cw.s[seg] + i);
  u16x4 o; o.x = f2bf(v[0]); o.y = f2bf(v[1]); o.z = f2bf(v[2]); o.w = f2bf(v[3]);
  *(u16x4*)(dst + off + i) = o;
}

// ---------------- x transpose-convert: (b,c,n) -> xbT[vb][q][c] ----------------
__global__ __launch_bounds__(256) void k_cvtx(const float* x0, const float* x1,
                                              const float* x2, u16* XT) {
  __shared__ float tile[64][65];
  const int t = threadIdx.x;
  const int q0 = blockIdx.x * 64, c0 = blockIdx.y * 64;
  const int vb = blockIdx.z, v = vb >> 2, b = vb & 3;
  const float* src = (v == 0 ? x0 : v == 1 ? x1 : x2) + ((size_t)b * C_ + c0) * N_ + q0;
  #pragma unroll
  for (int i = 0; i < 4; ++i) {
    int idx = t + i * 256;
    int r = idx >> 4, q4 = (idx & 15) * 4;
    f32x4 val = *(const f32x4*)(src + (size_t)r * N_ + q4);
    tile[r][q4 + 0] = val[0]; tile[r][q4 + 1] = val[1];
    tile[r][q4 + 2] = val[2]; tile[r][q4 + 3] = val[3];
  }
  __syncthreads();
  u16* dst = XT + ((size_t)vb * N_ + q0) * 256 + c0;
  const int q = t >> 2, cp = (t & 3) * 16;
  u16 tmp[16];
  #pragma unroll
  for (int jj = 0; jj < 16; ++jj) tmp[jj] = f2bf(tile[cp + jj][q]);
  #pragma unroll
  for (int s4 = 0; s4 < 4; ++s4) {
    u16x4 o; o.x = tmp[s4 * 4]; o.y = tmp[s4 * 4 + 1];
    o.z = tmp[s4 * 4 + 2]; o.w = tmp[s4 * 4 + 3];
    *(u16x4*)(dst + (size_t)q * 256 + cp + s4 * 4) = o;
  }
}

// ---------------- proj ----------------
struct ProjA { const float* bias[9]; };
__global__ __launch_bounds__(256) void k_proj(const u16* WB, const u16* XT,
                                              u16* TH, u16* PH, u16* GP, ProjA pa) {
  __shared__ char As[16384], Bs[16384];
  const int col0 = blockIdx.x * 128;                 // q
  const int p = blockIdx.z >> 2, b = blockIdx.z & 3;
  const int v = p / 3, pt = p % 3;
  const char* Ab = (const char*)(WB + (size_t)p * 32768);
  const char* Bb = (const char*)(XT + ((size_t)(v * 4 + b) * N_ + col0) * 256);
  f32x4 acc[4][4] = {};
  gemm_core(Ab, 512, Bb, 512, 4, acc, As, Bs);
  EPI_SETUP;
  const float* bias = pa.bias[p];
  if (pt == 0) {                                     // g -> (ci, m) natural
    u16* dst = GP + (size_t)(v * 4 + b) * CI_ * N_;
    #pragma unroll
    for (int mf = 0; mf < 4; ++mf) {
      const int row = rb + mf * 16;
      f32x4 bv = *(const f32x4*)(bias + row);
      #pragma unroll
      for (int nf = 0; nf < 4; ++nf) {
        const int col = col0 + cb + nf * 16;
        #pragma unroll
        for (int r = 0; r < 4; ++r)
          dst[(size_t)(row + r) * N_ + col] = f2bf(acc[mf][nf][r] + bv[r]);
      }
    }
  } else {                                           // theta/phi -> (q, ci)
    u16* dst = (pt == 1 ? TH : PH) + (size_t)(v * 4 + b) * N_ * CI_;
    #pragma unroll
    for (int mf = 0; mf < 4; ++mf) {
      const int row = rb + mf * 16;                  // ci
      f32x4 bv = *(const f32x4*)(bias + row);
      #pragma unroll
      for (int nf = 0; nf < 4; ++nf) {
        const int col = col0 + cb + nf * 16;         // q
        u16x4 o;
        o.x = f2bf(acc[mf][nf][0] + bv[0]); o.y = f2bf(acc[mf][nf][1] + bv[1]);
        o.z = f2bf(acc[mf][nf][2] + bv[2]); o.w = f2bf(acc[mf][nf][3] + bv[3]);
        *(u16x4*)(dst + (size_t)col * CI_ + row) = o;
      }
    }
  }
}

// ---------------- score: F[br][qloc][k] fp32 ----------------
__global__ __launch_bounds__(256) void k_score(const u16* TH, const u16* PH,
                                               float* F, int b, int h) {
  __shared__ char As[16384], Bs[16384];
  const int col0 = blockIdx.x * 128;   // k
  const int row0 = blockIdx.y * 128;   // q within half
  const int br = blockIdx.z;
  const char* Ab = (const char*)(TH + ((size_t)(br * 4 + b) * N_ + h * NH_ + row0) * CI_);
  const char* Bb = (const char*)(PH + ((size_t)(br * 4 + b) * N_ + col0) * CI_);
  f32x4 acc[4][4] = {};
  gemm_core(Ab, 256, Bb, 256, 2, acc, As, Bs);
  EPI_SETUP;
  float* dst = F + (size_t)br * NH_ * N_;
  #pragma unroll
  for (int mf = 0; mf < 4; ++mf)
    #pragma unroll
    for (int nf = 0; nf < 4; ++nf)
      #pragma unroll
      for (int r = 0; r < 4; ++r)
        dst[(size_t)(row0 + rb + mf * 16 + r) * N_ + col0 + cb + nf * 16] = acc[mf][nf][r];
}

// ---------------- softsum: A-row = sum of 3 softmaxes -> bf16 ----------------
__device__ __forceinline__ float blk_red(float v, bool is_max, float* red) {
  #pragma unroll
  for (int o = 32; o; o >>= 1) {
    float u = __shfl_xor(v, o);
    v = is_max ? fmaxf(v, u) : v + u;
  }
  int w = threadIdx.x >> 6;
  __syncthreads();
  if ((threadIdx.x & 63) == 0) red[w] = v;
  __syncthreads();
  float r = red[0];
  #pragma unroll
  for (int j = 1; j < 4; ++j) r = is_max ? fmaxf(r, red[j]) : r + red[j];
  return r;
}

__global__ __launch_bounds__(256) void k_softsum(const float* F, u16* Abf, int b, int h) {
  __shared__ float red[4];
  const int q = blockIdx.x, t = threadIdx.x;
  float raw[3][9];
  #pragma unroll
  for (int i = 0; i < 3; ++i)
    #pragma unroll
    for (int s = 0; s < 9; ++s)
      raw[i][s] = F[(size_t)i * NH_ * N_ + (size_t)q * N_ + t + s * 256];
  float outv[9] = {};
  #pragma unroll
  for (int i = 0; i < 3; ++i) {
    float m = -3.4e38f;
    #pragma unroll
    for (int s = 0; s < 9; ++s) m = fmaxf(m, raw[i][s]);
    m = blk_red(m, true, red);
    float ssum = 0.f;
    #pragma unroll
    for (int s = 0; s < 9; ++s) { raw[i][s] = expf(raw[i][s] - m); ssum += raw[i][s]; }
    ssum = blk_red(ssum, false, red);
    float inv = 1.f / ssum;
    #pragma unroll
    for (int s = 0; s < 9; ++s) outv[s] += raw[i][s] * inv;
  }
  u16* dst = Abf + ((size_t)b * N_ + h * NH_ + q) * N_;
  #pragma unroll
  for (int s = 0; s < 9; ++s) dst[t + s * 256] = f2bf(outv[s]);
}

// ---------------- pv: Y[b][q][jc] = A_bf x gP ----------------
__global__ __launch_bounds__(256) void k_pv(const u16* Abf, const u16* GP, u16* Y) {
  __shared__ char As[16384], Bs[16384];
  const int j = blockIdx.x;            // col block == branch
  const int row0 = blockIdx.y * 128;   // q
  const int b = blockIdx.z;
  const char* Ab = (const char*)(Abf + ((size_t)b * N_ + row0) * N_);
  const char* Bb = (const char*)(GP + (size_t)(j * 4 + b) * CI_ * N_);
  f32x4 acc[4][4] = {};
  gemm_core(Ab, 4608, Bb, 4608, 36, acc, As, Bs);
  EPI_SETUP;
  #pragma unroll
  for (int mf = 0; mf < 4; ++mf)
    #pragma unroll
    for (int nf = 0; nf < 4; ++nf)
      #pragma unroll
      for (int r = 0; r < 4; ++r)
        Y[((size_t)b * N_ + row0 + rb + mf * 16 + r) * 384 + j * 128 + cb + nf * 16] =
            f2bf(acc[mf][nf][r]);
}

// ---------------- zcat: dwcatT[b][q][cg] ----------------
struct ZA { const float* x[3]; const float* wzb[3]; const float* dww; const float* dwb; };
__global__ __launch_bounds__(256) void k_zcat(const u16* WZ, const u16* Y,
                                              u16* DW, ZA za) {
  __shared__ char As[16384], Bs[16384];
  const int col0 = blockIdx.x * 128;                 // q
  const int row0 = blockIdx.y * 128;                 // c within 256
  const int j = blockIdx.z >> 2, b = blockIdx.z & 3;
  const char* Ab = (const char*)(WZ + (size_t)j * 32768 + (size_t)row0 * CI_);
  const char* Bb = (const char*)(Y + ((size_t)b * N_ + col0) * 384 + j * CI_);
  f32x4 acc[4][4] = {};
  gemm_core(Ab, 256, Bb, 768, 2, acc, As, Bs);
  EPI_SETUP;
  const float* xj = za.x[j];
  #pragma unroll
  for (int mf = 0; mf < 4; ++mf) {
    const int cl = row0 + rb + mf * 16;              // 0..255
    const int cg = j * 256 + cl;
    f32x4 wb = *(const f32x4*)(za.wzb[j] + cl);
    f32x4 sc = *(const f32x4*)(za.dww + cg);
    f32x4 sb = *(const f32x4*)(za.dwb + cg);
    #pragma unroll
    for (int nf = 0; nf < 4; ++nf) {
      const int qg = col0 + cb + nf * 16;
      u16x4 o;
      o.x = f2bf((acc[mf][nf][0] + wb[0] + xj[((size_t)b * C_ + cl + 0) * N_ + qg]) * sc[0] + sb[0]);
      o.y = f2bf((acc[mf][nf][1] + wb[1] + xj[((size_t)b * C_ + cl + 1) * N_ + qg]) * sc[1] + sb[1]);
      o.z = f2bf((acc[mf][nf][2] + wb[2] + xj[((size_t)b * C_ + cl + 2) * N_ + qg]) * sc[2] + sb[2]);
      o.w = f2bf((acc[mf][nf][3] + wb[3] + xj[((size_t)b * C_ + cl + 3) * N_ + qg]) * sc[3] + sb[3]);
      *(u16x4*)(DW + ((size_t)b * N_ + qg) * 768 + cg) = o;
    }
  }
}

// ---------------- final: out = x_in + p*(pw @ dwcatT^T + pw_b) ----------------
__global__ __launch_bounds__(256) void k_final(const u16* PWb, const u16* DW,
                                               const float* pwb, const float* xin,
                                               const float* pp, float* out) {
  __shared__ char As[16384], Bs[16384];
  const int col0 = blockIdx.x * 128;   // q
  const int row0 = blockIdx.y * 128;   // o
  const int b = blockIdx.z;
  const char* Ab = (const char*)(PWb + (size_t)row0 * 768);
  const char* Bb = (const char*)(DW + ((size_t)b * N_ + col0) * 768);
  f32x4 acc[4][4] = {};
  gemm_core(Ab, 1536, Bb, 1536, 12, acc, As, Bs);
  EPI_SETUP;
  const float p = pp[0];
  #pragma unroll
  for (int mf = 0; mf < 4; ++mf) {
    const int o = row0 + rb + mf * 16;
    f32x4 bb = *(const f32x4*)(pwb + o);
    #pragma unroll
    for (int nf = 0; nf < 4; ++nf) {
      const int qg = col0 + cb + nf * 16;
      #pragma unroll
      for (int r = 0; r < 4; ++r) {
        size_t idx = ((size_t)b * 1024 + o + r) * N_ + qg;
        out[idx] = xin[idx] + p * (acc[mf][nf][r] + bb[r]);
      }
    }
  }
}

// ---------------------------------------------------------------------------
extern "C" void kernel_launch(void* const* d_in, const int* in_sizes, int n_in,
                              void* d_out, int out_size, void* d_ws, size_t ws_size,
                              hipStream_t stream) {
  const float* x0  = (const float*)d_in[0];
  const float* x1  = (const float*)d_in[1];
  const float* x2  = (const float*)d_in[2];
  const float* xin = (const float*)d_in[3];
  const float* g_w = (const float*)d_in[4];
  const float* g_b = (const float*)d_in[5];
  const float* thw[3] = {(const float*)d_in[6],  (const float*)d_in[10], (const float*)d_in[14]};
  const float* thb[3] = {(const float*)d_in[7],  (const float*)d_in[11], (const float*)d_in[15]};
  const float* phw[3] = {(const float*)d_in[8],  (const float*)d_in[12], (const float*)d_in[16]};
  const float* phb[3] = {(const float*)d_in[9],  (const float*)d_in[13], (const float*)d_in[17]};
  const float* Wm[3]  = {(const float*)d_in[18], (const float*)d_in[20], (const float*)d_in[22]};
  const float* Wmb[3] = {(const float*)d_in[19], (const float*)d_in[21], (const float*)d_in[23]};
  const float* dww = (const float*)d_in[24];
  const float* dwb = (const float*)d_in[25];
  const float* pww = (const float*)d_in[26];
  const float* pwb = (const float*)d_in[27];
  const float* pp  = (const float*)d_in[28];

  char* wsb = (char*)d_ws;
  u16*   WB  = (u16*)(wsb + B_WB);
  u16*   WZ  = (u16*)(wsb + B_WZ);
  u16*   PW  = (u16*)(wsb + B_PW);
  u16*   XT  = (u16*)(wsb + B_R1);
  u16*   Y   = (u16*)(wsb + B_R1);   // overlays XT (dead after k_proj)
  u16*   TH  = (u16*)(wsb + B_R2);
  u16*   PH  = TH + (size_t)3 * B_ * N_ * CI_;
  u16*   DW  = (u16*)(wsb + B_R2);   // overlays TH/PH (dead after last k_score)
  u16*   GP  = (u16*)(wsb + B_GP);
  float* F   = (float*)(wsb + B_F);
  u16*   Abf = (u16*)(wsb + B_A);

  CvtW cw;
  cw.s[0] = g_w; cw.s[1] = thw[0]; cw.s[2] = phw[0];
  cw.s[3] = g_w; cw.s[4] = thw[1]; cw.s[5] = phw[1];
  cw.s[6] = g_w; cw.s[7] = thw[2]; cw.s[8] = phw[2];
  cw.s[9] = Wm[0]; cw.s[10] = Wm[1]; cw.s[11] = Wm[2];
  cw.s[12] = pww;

  ProjA pa;
  pa.bias[0] = g_b; pa.bias[1] = thb[0]; pa.bias[2] = phb[0];
  pa.bias[3] = g_b; pa.bias[4] = thb[1]; pa.bias[5] = phb[1];
  pa.bias[6] = g_b; pa.bias[7] = thb[2]; pa.bias[8] = phb[2];

  ZA za;
  za.x[0] = x0; za.x[1] = x1; za.x[2] = x2;
  za.wzb[0] = Wmb[0]; za.wzb[1] = Wmb[1]; za.wzb[2] = Wmb[2];
  za.dww = dww; za.dwb = dwb;

  k_cvtw<<<dim3(768, 13), 256, 0, stream>>>(cw, WB);
  k_cvtx<<<dim3(36, 4, 12), 256, 0, stream>>>(x0, x1, x2, XT);
  k_proj<<<dim3(18, 1, 36), 256, 0, stream>>>(WB, XT, TH, PH, GP, pa);
  for (int b = 0; b < B_; ++b)
    for (int h = 0; h < 2; ++h) {
      k_score  <<<dim3(18, 9, 3), 256, 0, stream>>>(TH, PH, F, b, h);
      k_softsum<<<dim3(NH_),      256, 0, stream>>>(F, Abf, b, h);
    }
  k_pv   <<<dim3(3, 18, 4),  256, 0, stream>>>(Abf, GP, Y);
  k_zcat <<<dim3(18, 2, 12), 256, 0, stream>>>(WZ, Y, DW, za);
  k_final<<<dim3(18, 8, 4),  256, 0, stream>>>(PW, DW, pwb, xin, pp, (float*)d_out);
}

// Round 3
// 251.239 us; speedup vs baseline: 4.0124x; 1.4002x over previous
//
#include <hip/hip_runtime.h>

// ---------------------------------------------------------------------------
// NonLocalBlockND — bf16 MFMA pipeline, 2-phase double-buffered GEMM core.
//
// Round-3 changes vs round 2:
//  * gemm_core: 2-phase software pipeline (stage next K-tile into LDS buf^1
//    BEFORE computing buf; one barrier per K-step). LDS 64 KB, 2 blocks/CU.
//  * F scores stored fp16 (was fp32): full-batch F (3,2304,2304) fits the
//    same 31.85 MB slot -> 4 score launches (18,18,3) + 4 softsum launches.
//
// ws (bytes, total 112,066,560):
//   B_WB 0         bf16 proj weights (9x128x256, g duplicated)
//   B_WZ 589824    bf16 Wz (3x256x128)
//   B_PW 786432    bf16 pw (1024x768)
//   B_R1 2359296   xbT (3,4,2304,256) | later Y (4,2304,384)
//   B_R2 16515072  thT+phT (2x 3,4,2304,128) | later dwcatT (4,2304,768)
//   B_GP 30670848  gP (3,4,128,2304)
//   B_F  37748736  F (3,2304,2304) fp16, per current batch
//   B_A  69599232  A_bf (4,2304,2304) bf16
// ---------------------------------------------------------------------------

typedef __attribute__((ext_vector_type(8))) short bf16x8;
typedef __attribute__((ext_vector_type(4))) float f32x4;
typedef unsigned short u16;
struct alignas(8) u16x4 { u16 x, y, z, w; };

constexpr int B_ = 4, C_ = 256, N_ = 2304, CI_ = 128;
constexpr long long NN_ = (long long)N_ * N_;

constexpr size_t B_WB = 0;
constexpr size_t B_WZ = 589824;
constexpr size_t B_PW = 786432;
constexpr size_t B_R1 = 2359296;
constexpr size_t B_R2 = 16515072;
constexpr size_t B_GP = 30670848;
constexpr size_t B_F  = 37748736;
constexpr size_t B_A  = 69599232;

__device__ __forceinline__ u16 f2bf(float f) {
  unsigned u = __float_as_uint(f);
  u += 0x7fff + ((u >> 16) & 1);          // round-to-nearest-even
  return (u16)(u >> 16);
}
__device__ __forceinline__ u16 f2h(float f) {
  _Float16 h = (_Float16)f;
  return __builtin_bit_cast(u16, h);
}
__device__ __forceinline__ float h2f(u16 u) {
  return (float)__builtin_bit_cast(_Float16, u);
}

__device__ __forceinline__ void gload16(const void* g, void* l) {
  __builtin_amdgcn_global_load_lds((const __attribute__((address_space(1))) void*)g,
                                   (__attribute__((address_space(3))) void*)l,
                                   16, 0, 0);
}

// Stage one 128x64bf16 A-tile + B-tile (16 KB each) into LDS (linear layout).
__device__ __forceinline__ void stage128(const char* Ag, int ldaB,
                                         const char* Bg, int ldbB,
                                         char* As, char* Bs, int w, int l) {
  #pragma unroll
  for (int c = 0; c < 4; ++c) {
    const int idx = c * 4096 + w * 1024 + l * 16;
    const int row = idx >> 7, colb = idx & 127;
    gload16(Ag + (size_t)row * ldaB + colb, As + c * 4096 + w * 1024);
    gload16(Bg + (size_t)row * ldbB + colb, Bs + c * 4096 + w * 1024);
  }
}

// Compute one staged K-step: 2x (4 A-frags x 4 B-frags) 16x16x32 bf16 MFMA.
__device__ __forceinline__ void comp128(const char* As, const char* Bs,
                                        f32x4 (&acc)[4][4],
                                        int arow, int brow, int kb) {
  #pragma unroll
  for (int kk = 0; kk < 2; ++kk) {
    bf16x8 af[4], bfr[4];
    #pragma unroll
    for (int i = 0; i < 4; ++i) {
      af[i]  = *(const bf16x8*)(As + (arow + i * 16) * 128 + kk * 64 + kb);
      bfr[i] = *(const bf16x8*)(Bs + (brow + i * 16) * 128 + kk * 64 + kb);
    }
    #pragma unroll
    for (int mf = 0; mf < 4; ++mf)
      #pragma unroll
      for (int nf = 0; nf < 4; ++nf)
        acc[mf][nf] = __builtin_amdgcn_mfma_f32_16x16x32_bf16(
            af[mf], bfr[nf], acc[mf][nf], 0, 0, 0);
  }
}

// 128x128 output tile, BK=64, 256 threads (4 waves, 2x2 of 64x64).
// 2-phase double-buffered: stage(t+1) issued before compute(t); one barrier
// per K-step (compiler emits vmcnt(0) lgkmcnt(0) drain at __syncthreads).
__device__ __forceinline__ void gemm_core(const char* Ab, int ldaB,
                                          const char* Bb, int ldbB,
                                          int kIters, f32x4 (&acc)[4][4],
                                          char* lds) {
  const int t = (int)threadIdx.x, l = t & 63, w = t >> 6;
  const int arow = (w >> 1) * 64 + (l & 15);
  const int brow = (w & 1) * 64 + (l & 15);
  const int kb = ((l >> 4) * 8) * 2;
  char* Ac = lds;          char* Bc = lds + 16384;
  char* An = lds + 32768;  char* Bn = lds + 49152;
  stage128(Ab, ldaB, Bb, ldbB, Ac, Bc, w, l);
  __syncthreads();
  for (int kt = 0; kt < kIters - 1; ++kt) {
    stage128(Ab + (size_t)(kt + 1) * 128, ldaB,
             Bb + (size_t)(kt + 1) * 128, ldbB, An, Bn, w, l);
    comp128(Ac, Bc, acc, arow, brow, kb);
    __syncthreads();
    char* tp = Ac; Ac = An; An = tp;
    tp = Bc; Bc = Bn; Bn = tp;
  }
  comp128(Ac, Bc, acc, arow, brow, kb);
}

// C/D fragment -> (row, col): row = rb + mf*16 + r, col = cb + nf*16  [m89]
#define EPI_SETUP \
  const int el = (int)threadIdx.x & 63, ew = (int)threadIdx.x >> 6; \
  const int rb = (ew >> 1) * 64 + ((el >> 4) << 2); \
  const int cb = (ew & 1) * 64 + (el & 15);

// ---------------- weight convert ----------------
struct CvtW { const float* s[13]; };
__global__ __launch_bounds__(256) void k_cvtw(CvtW cw, u16* dst) {
  const int seg = blockIdx.y;
  const int i = (blockIdx.x * 256 + threadIdx.x) * 4;
  const int sz = (seg == 12) ? 786432 : 32768;
  if (i >= sz) return;
  size_t off = (seg < 9) ? (size_t)seg * 32768
             : (seg < 12) ? 294912 + (size_t)(seg - 9) * 32768
                          : 393216;
  f32x4 v = *(const f32x4*)(cw.s[seg] + i);
  u16x4 o; o.x = f2bf(v[0]); o.y = f2bf(v[1]); o.z = f2bf(v[2]); o.w = f2bf(v[3]);
  *(u16x4*)(dst + off + i) = o;
}

// ---------------- x transpose-convert: (b,c,n) -> xbT[vb][q][c] ----------------
__global__ __launch_bounds__(256) void k_cvtx(const float* x0, const float* x1,
                                              const float* x2, u16* XT) {
  __shared__ float tile[64][65];
  const int t = threadIdx.x;
  const int q0 = blockIdx.x * 64, c0 = blockIdx.y * 64;
  const int vb = blockIdx.z, v = vb >> 2, b = vb & 3;
  const float* src = (v == 0 ? x0 : v == 1 ? x1 : x2) + ((size_t)b * C_ + c0) * N_ + q0;
  #pragma unroll
  for (int i = 0; i < 4; ++i) {
    int idx = t + i * 256;
    int r = idx >> 4, q4 = (idx & 15) * 4;
    f32x4 val = *(const f32x4*)(src + (size_t)r * N_ + q4);
    tile[r][q4 + 0] = val[0]; tile[r][q4 + 1] = val[1];
    tile[r][q4 + 2] = val[2]; tile[r][q4 + 3] = val[3];
  }
  __syncthreads();
  u16* dst = XT + ((size_t)vb * N_ + q0) * 256 + c0;
  const int q = t >> 2, cp = (t & 3) * 16;
  u16 tmp[16];
  #pragma unroll
  for (int jj = 0; jj < 16; ++jj) tmp[jj] = f2bf(tile[cp + jj][q]);
  #pragma unroll
  for (int s4 = 0; s4 < 4; ++s4) {
    u16x4 o; o.x = tmp[s4 * 4]; o.y = tmp[s4 * 4 + 1];
    o.z = tmp[s4 * 4 + 2]; o.w = tmp[s4 * 4 + 3];
    *(u16x4*)(dst + (size_t)q * 256 + cp + s4 * 4) = o;
  }
}

// ---------------- proj ----------------
struct ProjA { const float* bias[9]; };
__global__ __launch_bounds__(256) void k_proj(const u16* WB, const u16* XT,
                                              u16* TH, u16* PH, u16* GP, ProjA pa) {
  __shared__ char lds[65536];
  const int col0 = blockIdx.x * 128;                 // q
  const int p = blockIdx.z >> 2, b = blockIdx.z & 3;
  const int v = p / 3, pt = p % 3;
  const char* Ab = (const char*)(WB + (size_t)p * 32768);
  const char* Bb = (const char*)(XT + ((size_t)(v * 4 + b) * N_ + col0) * 256);
  f32x4 acc[4][4] = {};
  gemm_core(Ab, 512, Bb, 512, 4, acc, lds);
  EPI_SETUP;
  const float* bias = pa.bias[p];
  if (pt == 0) {                                     // g -> (ci, m) natural
    u16* dst = GP + (size_t)(v * 4 + b) * CI_ * N_;
    #pragma unroll
    for (int mf = 0; mf < 4; ++mf) {
      const int row = rb + mf * 16;
      f32x4 bv = *(const f32x4*)(bias + row);
      #pragma unroll
      for (int nf = 0; nf < 4; ++nf) {
        const int col = col0 + cb + nf * 16;
        #pragma unroll
        for (int r = 0; r < 4; ++r)
          dst[(size_t)(row + r) * N_ + col] = f2bf(acc[mf][nf][r] + bv[r]);
      }
    }
  } else {                                           // theta/phi -> (q, ci)
    u16* dst = (pt == 1 ? TH : PH) + (size_t)(v * 4 + b) * N_ * CI_;
    #pragma unroll
    for (int mf = 0; mf < 4; ++mf) {
      const int row = rb + mf * 16;                  // ci
      f32x4 bv = *(const f32x4*)(bias + row);
      #pragma unroll
      for (int nf = 0; nf < 4; ++nf) {
        const int col = col0 + cb + nf * 16;         // q
        u16x4 o;
        o.x = f2bf(acc[mf][nf][0] + bv[0]); o.y = f2bf(acc[mf][nf][1] + bv[1]);
        o.z = f2bf(acc[mf][nf][2] + bv[2]); o.w = f2bf(acc[mf][nf][3] + bv[3]);
        *(u16x4*)(dst + (size_t)col * CI_ + row) = o;
      }
    }
  }
}

// ---------------- score: F[br][q][k] fp16 (full batch) ----------------
__global__ __launch_bounds__(256) void k_score(const u16* TH, const u16* PH,
                                               u16* F, int b) {
  __shared__ char lds[65536];
  const int col0 = blockIdx.x * 128;   // k
  const int row0 = blockIdx.y * 128;   // q
  const int br = blockIdx.z;
  const char* Ab = (const char*)(TH + ((size_t)(br * 4 + b) * N_ + row0) * CI_);
  const char* Bb = (const char*)(PH + ((size_t)(br * 4 + b) * N_ + col0) * CI_);
  f32x4 acc[4][4] = {};
  gemm_core(Ab, 256, Bb, 256, 2, acc, lds);
  EPI_SETUP;
  u16* dst = F + (size_t)br * NN_;
  #pragma unroll
  for (int mf = 0; mf < 4; ++mf)
    #pragma unroll
    for (int nf = 0; nf < 4; ++nf)
      #pragma unroll
      for (int r = 0; r < 4; ++r)
        dst[(size_t)(row0 + rb + mf * 16 + r) * N_ + col0 + cb + nf * 16] =
            f2h(acc[mf][nf][r]);
}

// ---------------- softsum: A-row = sum of 3 softmaxes -> bf16 ----------------
__device__ __forceinline__ float blk_red(float v, bool is_max, float* red) {
  #pragma unroll
  for (int o = 32; o; o >>= 1) {
    float u = __shfl_xor(v, o);
    v = is_max ? fmaxf(v, u) : v + u;
  }
  int w = threadIdx.x >> 6;
  __syncthreads();
  if ((threadIdx.x & 63) == 0) red[w] = v;
  __syncthreads();
  float r = red[0];
  #pragma unroll
  for (int j = 1; j < 4; ++j) r = is_max ? fmaxf(r, red[j]) : r + red[j];
  return r;
}

__global__ __launch_bounds__(256) void k_softsum(const u16* F, u16* Abf, int b) {
  __shared__ float red[4];
  const int q = blockIdx.x, t = threadIdx.x;
  float raw[3][9];
  #pragma unroll
  for (int i = 0; i < 3; ++i)
    #pragma unroll
    for (int s = 0; s < 9; ++s)
      raw[i][s] = h2f(F[(size_t)i * NN_ + (size_t)q * N_ + t + s * 256]);
  float outv[9] = {};
  #pragma unroll
  for (int i = 0; i < 3; ++i) {
    float m = -3.4e38f;
    #pragma unroll
    for (int s = 0; s < 9; ++s) m = fmaxf(m, raw[i][s]);
    m = blk_red(m, true, red);
    float ssum = 0.f;
    #pragma unroll
    for (int s = 0; s < 9; ++s) { raw[i][s] = expf(raw[i][s] - m); ssum += raw[i][s]; }
    ssum = blk_red(ssum, false, red);
    float inv = 1.f / ssum;
    #pragma unroll
    for (int s = 0; s < 9; ++s) outv[s] += raw[i][s] * inv;
  }
  u16* dst = Abf + ((size_t)b * N_ + q) * N_;
  #pragma unroll
  for (int s = 0; s < 9; ++s) dst[t + s * 256] = f2bf(outv[s]);
}

// ---------------- pv: Y[b][q][jc] = A_bf x gP ----------------
__global__ __launch_bounds__(256) void k_pv(const u16* Abf, const u16* GP, u16* Y) {
  __shared__ char lds[65536];
  const int j = blockIdx.x;            // col block == branch
  const int row0 = blockIdx.y * 128;   // q
  const int b = blockIdx.z;
  const char* Ab = (const char*)(Abf + ((size_t)b * N_ + row0) * N_);
  const char* Bb = (const char*)(GP + (size_t)(j * 4 + b) * CI_ * N_);
  f32x4 acc[4][4] = {};
  gemm_core(Ab, 4608, Bb, 4608, 36, acc, lds);
  EPI_SETUP;
  #pragma unroll
  for (int mf = 0; mf < 4; ++mf)
    #pragma unroll
    for (int nf = 0; nf < 4; ++nf)
      #pragma unroll
      for (int r = 0; r < 4; ++r)
        Y[((size_t)b * N_ + row0 + rb + mf * 16 + r) * 384 + j * 128 + cb + nf * 16] =
            f2bf(acc[mf][nf][r]);
}

// ---------------- zcat: dwcatT[b][q][cg] ----------------
struct ZA { const float* x[3]; const float* wzb[3]; const float* dww; const float* dwb; };
__global__ __launch_bounds__(256) void k_zcat(const u16* WZ, const u16* Y,
                                              u16* DW, ZA za) {
  __shared__ char lds[65536];
  const int col0 = blockIdx.x * 128;                 // q
  const int row0 = blockIdx.y * 128;                 // c within 256
  const int j = blockIdx.z >> 2, b = blockIdx.z & 3;
  const char* Ab = (const char*)(WZ + (size_t)j * 32768 + (size_t)row0 * CI_);
  const char* Bb = (const char*)(Y + ((size_t)b * N_ + col0) * 384 + j * CI_);
  f32x4 acc[4][4] = {};
  gemm_core(Ab, 256, Bb, 768, 2, acc, lds);
  EPI_SETUP;
  const float* xj = za.x[j];
  #pragma unroll
  for (int mf = 0; mf < 4; ++mf) {
    const int cl = row0 + rb + mf * 16;              // 0..255
    const int cg = j * 256 + cl;
    f32x4 wb = *(const f32x4*)(za.wzb[j] + cl);
    f32x4 sc = *(const f32x4*)(za.dww + cg);
    f32x4 sb = *(const f32x4*)(za.dwb + cg);
    #pragma unroll
    for (int nf = 0; nf < 4; ++nf) {
      const int qg = col0 + cb + nf * 16;
      u16x4 o;
      o.x = f2bf((acc[mf][nf][0] + wb[0] + xj[((size_t)b * C_ + cl + 0) * N_ + qg]) * sc[0] + sb[0]);
      o.y = f2bf((acc[mf][nf][1] + wb[1] + xj[((size_t)b * C_ + cl + 1) * N_ + qg]) * sc[1] + sb[1]);
      o.z = f2bf((acc[mf][nf][2] + wb[2] + xj[((size_t)b * C_ + cl + 2) * N_ + qg]) * sc[2] + sb[2]);
      o.w = f2bf((acc[mf][nf][3] + wb[3] + xj[((size_t)b * C_ + cl + 3) * N_ + qg]) * sc[3] + sb[3]);
      *(u16x4*)(DW + ((size_t)b * N_ + qg) * 768 + cg) = o;
    }
  }
}

// ---------------- final: out = x_in + p*(pw @ dwcatT^T + pw_b) ----------------
__global__ __launch_bounds__(256) void k_final(const u16* PWb, const u16* DW,
                                               const float* pwb, const float* xin,
                                               const float* pp, float* out) {
  __shared__ char lds[65536];
  const int col0 = blockIdx.x * 128;   // q
  const int row0 = blockIdx.y * 128;   // o
  const int b = blockIdx.z;
  const char* Ab = (const char*)(PWb + (size_t)row0 * 768);
  const char* Bb = (const char*)(DW + ((size_t)b * N_ + col0) * 768);
  f32x4 acc[4][4] = {};
  gemm_core(Ab, 1536, Bb, 1536, 12, acc, lds);
  EPI_SETUP;
  const float p = pp[0];
  #pragma unroll
  for (int mf = 0; mf < 4; ++mf) {
    const int o = row0 + rb + mf * 16;
    f32x4 bb = *(const f32x4*)(pwb + o);
    #pragma unroll
    for (int nf = 0; nf < 4; ++nf) {
      const int qg = col0 + cb + nf * 16;
      #pragma unroll
      for (int r = 0; r < 4; ++r) {
        size_t idx = ((size_t)b * 1024 + o + r) * N_ + qg;
        out[idx] = xin[idx] + p * (acc[mf][nf][r] + bb[r]);
      }
    }
  }
}

// ---------------------------------------------------------------------------
extern "C" void kernel_launch(void* const* d_in, const int* in_sizes, int n_in,
                              void* d_out, int out_size, void* d_ws, size_t ws_size,
                              hipStream_t stream) {
  const float* x0  = (const float*)d_in[0];
  const float* x1  = (const float*)d_in[1];
  const float* x2  = (const float*)d_in[2];
  const float* xin = (const float*)d_in[3];
  const float* g_w = (const float*)d_in[4];
  const float* g_b = (const float*)d_in[5];
  const float* thw[3] = {(const float*)d_in[6],  (const float*)d_in[10], (const float*)d_in[14]};
  const float* thb[3] = {(const float*)d_in[7],  (const float*)d_in[11], (const float*)d_in[15]};
  const float* phw[3] = {(const float*)d_in[8],  (const float*)d_in[12], (const float*)d_in[16]};
  const float* phb[3] = {(const float*)d_in[9],  (const float*)d_in[13], (const float*)d_in[17]};
  const float* Wm[3]  = {(const float*)d_in[18], (const float*)d_in[20], (const float*)d_in[22]};
  const float* Wmb[3] = {(const float*)d_in[19], (const float*)d_in[21], (const float*)d_in[23]};
  const float* dww = (const float*)d_in[24];
  const float* dwb = (const float*)d_in[25];
  const float* pww = (const float*)d_in[26];
  const float* pwb = (const float*)d_in[27];
  const float* pp  = (const float*)d_in[28];

  char* wsb = (char*)d_ws;
  u16*   WB  = (u16*)(wsb + B_WB);
  u16*   WZ  = (u16*)(wsb + B_WZ);
  u16*   PW  = (u16*)(wsb + B_PW);
  u16*   XT  = (u16*)(wsb + B_R1);
  u16*   Y   = (u16*)(wsb + B_R1);   // overlays XT (dead after k_proj)
  u16*   TH  = (u16*)(wsb + B_R2);
  u16*   PH  = TH + (size_t)3 * B_ * N_ * CI_;
  u16*   DW  = (u16*)(wsb + B_R2);   // overlays TH/PH (dead after last k_score)
  u16*   GP  = (u16*)(wsb + B_GP);
  u16*   Fh  = (u16*)(wsb + B_F);    // fp16 scores, (3,2304,2304), per batch
  u16*   Abf = (u16*)(wsb + B_A);

  CvtW cw;
  cw.s[0] = g_w; cw.s[1] = thw[0]; cw.s[2] = phw[0];
  cw.s[3] = g_w; cw.s[4] = thw[1]; cw.s[5] = phw[1];
  cw.s[6] = g_w; cw.s[7] = thw[2]; cw.s[8] = phw[2];
  cw.s[9] = Wm[0]; cw.s[10] = Wm[1]; cw.s[11] = Wm[2];
  cw.s[12] = pww;

  ProjA pa;
  pa.bias[0] = g_b; pa.bias[1] = thb[0]; pa.bias[2] = phb[0];
  pa.bias[3] = g_b; pa.bias[4] = thb[1]; pa.bias[5] = phb[1];
  pa.bias[6] = g_b; pa.bias[7] = thb[2]; pa.bias[8] = phb[2];

  ZA za;
  za.x[0] = x0; za.x[1] = x1; za.x[2] = x2;
  za.wzb[0] = Wmb[0]; za.wzb[1] = Wmb[1]; za.wzb[2] = Wmb[2];
  za.dww = dww; za.dwb = dwb;

  k_cvtw<<<dim3(768, 13), 256, 0, stream>>>(cw, WB);
  k_cvtx<<<dim3(36, 4, 12), 256, 0, stream>>>(x0, x1, x2, XT);
  k_proj<<<dim3(18, 1, 36), 256, 0, stream>>>(WB, XT, TH, PH, GP, pa);
  for (int b = 0; b < B_; ++b) {
    k_score  <<<dim3(18, 18, 3), 256, 0, stream>>>(TH, PH, Fh, b);
    k_softsum<<<dim3(N_),        256, 0, stream>>>(Fh, Abf, b);
  }
  k_pv   <<<dim3(3, 18, 4),  256, 0, stream>>>(Abf, GP, Y);
  k_zcat <<<dim3(18, 2, 12), 256, 0, stream>>>(WZ, Y, DW, za);
  k_final<<<dim3(18, 8, 4),  256, 0, stream>>>(PW, DW, pwb, xin, pp, (float*)d_out);
}